// Round 12
// baseline (303.904 us; speedup 1.0000x reference)
//
#include <hip/hip_runtime.h>

#define HW (512*512)

typedef __attribute__((ext_vector_type(8))) short bfrag;   // 8 x bf16
typedef __attribute__((ext_vector_type(4))) float ffrag;   // 4 x f32 acc
typedef __attribute__((ext_vector_type(4))) float fx4;
typedef __attribute__((ext_vector_type(4))) unsigned int ux4;
typedef __attribute__((ext_vector_type(2))) unsigned int ux2;

__device__ __forceinline__ unsigned short f2bf(float f) {
  unsigned int u = __float_as_uint(f);
  u += 0x7fffu + ((u >> 16) & 1u);        // round-to-nearest-even
  return (unsigned short)(u >> 16);
}
__device__ __forceinline__ unsigned int pk2(float a, float b) {
  return (unsigned int)f2bf(a) | ((unsigned int)f2bf(b) << 16);
}
// LDS address swizzle: XOR 16B-slot bits [7:4] with bits [11:8].
__device__ __forceinline__ int swz(int a) { return a ^ ((a >> 4) & 0xF0); }

// ---------- Kernel W: pack conv weights, taps folded into K ----------------
__global__ __launch_bounds__(256) void pack_w_k(
    const float* __restrict__ cw, unsigned short* __restrict__ wp) {
  int gid = blockIdx.x * 256 + threadIdx.x;
  if (gid >= 96 * 64) return;
  int fid = gid >> 6, lane = gid & 63;
  int t = fid / 3, m = fid - t * 3;
  int q = lane >> 4, co = lane & 15;
  int tap = 4 * m + q;
  unsigned short v[8];
#pragma unroll
  for (int j = 0; j < 8; ++j) {
    int ci = t * 8 + j;
    float f = (co < 8 && tap < 9) ? cw[(co * 256 + ci) * 9 + tap] : 0.0f;
    v[j] = f2bf(f);
  }
  *(uint4*)(wp + gid * 8) = *(const uint4*)v;
}

// ------- Fused 3x3 conv: 8-row x 128-wide strips, ci-split, 2 blk/CU -------
// 512 blocks = 64 vstrips x 4 cols x 2 ci-halves; 512 thr (8 waves = 8 rows).
// Per chunk (8 ci): stage 10 rows x 136 px (dup 1.33x, 544B runs) into
// swizzled dbuf LDS; depth-1 prefetch (R8 pattern); 1 barrier per chunk.
// Output: f32 partials (bias folded into half 0).
constexpr int RSB  = 136 * 16;      // 2176 B per LDS row
constexpr int BUFB = 10 * RSB;      // 21760 B per buffer

__global__ __launch_bounds__(512, 4) void conv_fused_k(
    const float* __restrict__ x, const unsigned short* __restrict__ wp,
    const float* __restrict__ cb, float* __restrict__ part) {
  __shared__ __align__(16) char xs[2 * BUFB];     // 43520 B
  const int tid  = threadIdx.x;
  const int wid  = tid >> 6, lane = tid & 63;
  const int q    = lane >> 4, p = lane & 15;
  const int ro   = wid;                            // out-row within strip

  // XCD-swizzle: each XCD owns a contiguous 64-row band (both ci-halves)
  const int bid = blockIdx.x;
  const int xcd = bid & 7, idx = bid >> 3;
  const int vstrip = xcd * 8 + (idx & 7);
  const int col    = (idx >> 3) & 3;
  const int half   = idx >> 5;                     // ci-half 0/1
  const int h0 = vstrip * 8, w0 = col * 128;

  // ---- staging unit descriptors (t-invariant): 680 units ----
  const int row1 = tid / 68, rem1 = tid - row1 * 68;
  const int cc1 = rem1 >> 1, h41 = rem1 & 1;
  const int gh1 = h0 - 1 + row1, gpx1 = w0 + cc1 * 4 - 4;
  const bool ok1 = ((unsigned)gh1 < 512u) && ((unsigned)gpx1 < 509u);
  const float* gp1 = x + (size_t)(half * 128 + h41 * 4) * HW
                   + min(max(gh1, 0), 511) * 512 + min(max(gpx1, 0), 508);
  const int wb1 = row1 * RSB + cc1 * 64 + h41 * 8;

  const int u2 = 512 + tid;
  const bool act2 = (tid < 168);
  const int row2 = u2 / 68, rem2 = u2 - row2 * 68;
  const int cc2 = rem2 >> 1, h42 = rem2 & 1;
  const int gh2 = h0 - 1 + row2, gpx2 = w0 + cc2 * 4 - 4;
  const bool ok2 = act2 && ((unsigned)gh2 < 512u) && ((unsigned)gpx2 < 509u);
  const float* gp2 = x + (size_t)(half * 128 + h42 * 4) * HW
                   + min(max(gh2, 0), 511) * 512 + min(max(gpx2, 0), 508);
  const int wb2 = row2 * RSB + cc2 * 64 + h42 * 8;

  // ---- per-m LDS read offsets ----
  int mo[3];
#pragma unroll
  for (int m = 0; m < 3; ++m) {
    int tap = 4 * m + q; if (tap > 8) tap = 8;
    int dy = (tap * 11) >> 5;
    int dx = tap - 3 * dy;
    mo[m] = dy * RSB + dx * 16;
  }
  const int base0 = ro * RSB + (p + 3) * 16;

  fx4 S1a, S1b, S1c, S1d, S2a, S2b, S2c, S2d;

#define ISSUE(t)                                                          \
  { const float* g1_ = gp1 + (size_t)((t) * 8) * HW;                      \
    S1a = *(const fx4*)(g1_);                                             \
    S1b = *(const fx4*)(g1_ + (size_t)HW);                                \
    S1c = *(const fx4*)(g1_ + 2 * (size_t)HW);                            \
    S1d = *(const fx4*)(g1_ + 3 * (size_t)HW);                            \
    if (act2) {                                                           \
      const float* g2_ = gp2 + (size_t)((t) * 8) * HW;                    \
      S2a = *(const fx4*)(g2_);                                           \
      S2b = *(const fx4*)(g2_ + (size_t)HW);                              \
      S2c = *(const fx4*)(g2_ + 2 * (size_t)HW);                          \
      S2d = *(const fx4*)(g2_ + 3 * (size_t)HW);                          \
    } }

#define WRITE(tb_)                                                        \
  { _Pragma("unroll") for (int j_ = 0; j_ < 4; ++j_) {                    \
      ux2 v_;                                                             \
      v_.x = pk2(S1a[j_], S1b[j_]); v_.y = pk2(S1c[j_], S1d[j_]);         \
      if (!ok1) { v_.x = 0u; v_.y = 0u; }                                 \
      *(ux2*)(xs + swz((tb_) + wb1 + j_ * 16)) = v_;                      \
    }                                                                     \
    if (act2) {                                                           \
      _Pragma("unroll") for (int j_ = 0; j_ < 4; ++j_) {                  \
        ux2 v_;                                                           \
        v_.x = pk2(S2a[j_], S2b[j_]); v_.y = pk2(S2c[j_], S2d[j_]);       \
        if (!ok2) { v_.x = 0u; v_.y = 0u; }                               \
        *(ux2*)(xs + swz((tb_) + wb2 + j_ * 16)) = v_;                    \
      }                                                                   \
    } }

#define MFMA_PHASE(tb_)                                                   \
  { _Pragma("unroll") for (int kk = 0; kk < 8; ++kk) {                    \
      const int ab = (tb_) + base0 + kk * 256;                            \
      bfrag b0 = *(const bfrag*)(xs + swz(ab + mo[0]));                   \
      acc[kk] = __builtin_amdgcn_mfma_f32_16x16x32_bf16(a0, b0, acc[kk], 0, 0, 0); \
      bfrag b1 = *(const bfrag*)(xs + swz(ab + mo[1]));                   \
      acc[kk] = __builtin_amdgcn_mfma_f32_16x16x32_bf16(a1, b1, acc[kk], 0, 0, 0); \
      bfrag b2 = *(const bfrag*)(xs + swz(ab + mo[2]));                   \
      acc[kk] = __builtin_amdgcn_mfma_f32_16x16x32_bf16(a2, b2, acc[kk], 0, 0, 0); \
    } }

  ffrag acc[8];
#pragma unroll
  for (int i = 0; i < 8; ++i) acc[i] = ffrag{0.f, 0.f, 0.f, 0.f};

  ISSUE(0);
  WRITE(0);
  __syncthreads();

#pragma unroll 1
  for (int t = 0; t < 16; ++t) {
    // A fragments first (their vmcnt wait won't drain staging loads)
    const unsigned short* wpt =
        wp + (size_t)((half * 16 + t) * 3) * 512 + lane * 8;
    bfrag a0 = *(const bfrag*)(wpt);
    bfrag a1 = *(const bfrag*)(wpt + 512);
    bfrag a2 = *(const bfrag*)(wpt + 1024);

    if (t < 15) ISSUE(t + 1);          // next chunk flies across MFMAs

    MFMA_PHASE((t & 1) * BUFB);

    if (t < 15) {
      WRITE(((t + 1) & 1) * BUFB);     // vmcnt drain lands after compute
      __syncthreads();
    }
  }
#undef ISSUE
#undef WRITE
#undef MFMA_PHASE

  // epilogue: partial sums (f32); bias folded into half 0
  if (lane < 32) {
    float* pp = part + (size_t)half * 2097152;
    const int orow = h0 + ro;
#pragma unroll
    for (int kk = 0; kk < 8; ++kk)
#pragma unroll
      for (int reg = 0; reg < 4; ++reg) {
        int co = q * 4 + reg;
        float b = half ? 0.0f : cb[co];
        pp[co * HW + orow * 512 + w0 + kk * 16 + p] = acc[kk][reg] + b;
      }
  }
}

// --- Kernel B: sum partials -> xc, argmax one-hot -> 8x8 mean -> unfold ----
__global__ __launch_bounds__(256) void argmax_pool_unfold_k(
    const float* __restrict__ part, float* __restrict__ xc,
    float* __restrict__ U) {
  const int lane = threadIdx.x & 63;
  const int wv   = threadIdx.x >> 6;
  const int cell = blockIdx.x * 4 + wv;      // 0..4095
  const int hd = cell >> 6, wd = cell & 63;  // fm coords (64x64)
  const int h = hd * 8 + (lane >> 3), w = wd * 8 + (lane & 7);
  const int pix = h * 512 + w;
  const float* p1 = part + 2097152;

  float best = -1e30f;
  int bc = 0;
#pragma unroll
  for (int c = 0; c < 8; ++c) {
    float v = part[c * HW + pix] + p1[c * HW + pix];
    xc[c * HW + pix] = v;                    // materialize x_conv
    if (v > best) { best = v; bc = c; }      // first-max kept (strict >)
  }
  float myu = 0.f;
#pragma unroll
  for (int c = 0; c < 8; ++c) {
    unsigned long long mk = __ballot(bc == c);
    if (lane == c) myu = (float)__popcll(mk) * (1.0f / 64.0f);
  }
  if (lane < 8) {
    const int k = (hd & 7) * 8 + (wd & 7);   // kernel element
    const int m = (hd >> 3) * 8 + (wd >> 3); // patch position
    U[lane * 4096 + k * 64 + m] = myu;
  }
}

// ---- Kernel C: att=(A/nz)·U, fold, 1x1 conv, out=corr*x+x, + attn copy ----
// 256 blocks x 512 thr; U (128 KB) loaded once into LDS, 1 barrier; 16
// patches/block, everything after the fill is wave-local.
__global__ __launch_bounds__(512) void att_fold_corr_k(
    const float* __restrict__ attn, const float* __restrict__ U,
    const float* __restrict__ cw, const float* __restrict__ cb,
    float* __restrict__ out, float* __restrict__ attn_out) {
  __shared__ float Ul[32768];                // 128 KB: U[c][k][m]
  __shared__ float Ar[8][64];
  const int tid  = threadIdx.x;
  const int lane = tid & 63;
  const int wv   = tid >> 6;

  for (int i = tid; i < 8192; i += 512)
    ((fx4*)Ul)[i] = ((const fx4*)U)[i];
  __syncthreads();

#pragma unroll
  for (int i = 0; i < 2; ++i) {
    const int l = blockIdx.x * 16 + wv * 2 + i;
    const int hq = l >> 6, wq = l & 63;
    const int h = hq * 8 + (lane >> 3), w = wq * 8 + (lane & 7);

    float corrv[8];
#pragma unroll
    for (int c = 0; c < 8; ++c) {
      const int aidx = ((c << 12) + l) * 64 + lane;
      float av = attn[aidx];
      attn_out[aidx] = av;                   // output 1: verbatim copy
      unsigned long long nzm = __ballot(av != 0.0f);
      float inv = 1.0f / ((float)__popcll(nzm) + 1e-5f);
      Ar[wv][lane] = av * inv;               // same-wave LDS RAW: safe
      const float* u = Ul + c * 4096;
      float s = 0.f;
#pragma unroll
      for (int k = 0; k < 64; ++k)
        s = fmaf(Ar[wv][k], u[k * 64 + lane], s);
      corrv[c] = s;
    }

    const int pix = h * 512 + w;
#pragma unroll
    for (int d = 0; d < 8; ++d) {
      float s = cb[d];
#pragma unroll
      for (int c = 0; c < 8; ++c)
        s = fmaf(corrv[c], cw[d * 8 + c], s);
      float v = out[d * HW + pix];
      out[d * HW + pix] = fmaf(s, v, v);
    }
  }
}

extern "C" void kernel_launch(void* const* d_in, const int* in_sizes, int n_in,
                              void* d_out, int out_size, void* d_ws, size_t ws_size,
                              hipStream_t stream) {
  const float* x    = (const float*)d_in[0];
  const float* attn = (const float*)d_in[1];
  const float* cw   = (const float*)d_in[2];
  const float* cb   = (const float*)d_in[3];
  const float* qw   = (const float*)d_in[4];
  const float* qb   = (const float*)d_in[5];
  float* out = (float*)d_out;

  char* ws = (char*)d_ws;
  unsigned short* wpack = (unsigned short*)ws;   // 96 frags * 1KB = 96 KB
  float* U    = (float*)(ws + 98304);            // 128 KB
  float* part = (float*)(ws + 98304 + 131072);   // 2 x 8 MB f32 partials
  float* xc = out;                               // x_conv lives in out[0:2M]

  pack_w_k<<<dim3(24), dim3(256), 0, stream>>>(cw, wpack);
  conv_fused_k<<<dim3(512), dim3(512), 0, stream>>>(x, wpack, cb, part);
  argmax_pool_unfold_k<<<dim3(1024), dim3(256), 0, stream>>>(part, xc, U);
  att_fold_corr_k<<<dim3(256), dim3(512), 0, stream>>>(attn, U, qw, qb,
                                                       out, out + 2097152);
}

// Round 13
// 97.566 us; speedup vs baseline: 3.1148x; 3.1148x over previous
//
#include <hip/hip_runtime.h>

#define HW (512*512)

typedef __attribute__((ext_vector_type(8))) short bfrag;   // 8 x bf16
typedef __attribute__((ext_vector_type(4))) float ffrag;   // 4 x f32 acc
typedef __attribute__((ext_vector_type(4))) float fx4;
typedef __attribute__((ext_vector_type(4))) unsigned int ux4;
typedef __attribute__((ext_vector_type(2))) unsigned int ux2;

__device__ __forceinline__ unsigned short f2bf(float f) {
  unsigned int u = __float_as_uint(f);
  u += 0x7fffu + ((u >> 16) & 1u);        // round-to-nearest-even
  return (unsigned short)(u >> 16);
}
__device__ __forceinline__ unsigned int pk2(float a, float b) {
  return (unsigned int)f2bf(a) | ((unsigned int)f2bf(b) << 16);
}
// LDS address swizzle: XOR 16B-slot bits [7:4] with bits [11:8].
__device__ __forceinline__ int swz(int a) { return a ^ ((a >> 4) & 0xF0); }

// ---------- Kernel W: pack conv weights, taps folded into K ----------------
__global__ __launch_bounds__(256) void pack_w_k(
    const float* __restrict__ cw, unsigned short* __restrict__ wp) {
  int gid = blockIdx.x * 256 + threadIdx.x;
  if (gid >= 96 * 64) return;
  int fid = gid >> 6, lane = gid & 63;
  int t = fid / 3, m = fid - t * 3;
  int q = lane >> 4, co = lane & 15;
  int tap = 4 * m + q;
  unsigned short v[8];
#pragma unroll
  for (int j = 0; j < 8; ++j) {
    int ci = t * 8 + j;
    float f = (co < 8 && tap < 9) ? cw[(co * 256 + ci) * 9 + tap] : 0.0f;
    v[j] = f2bf(f);
  }
  *(uint4*)(wp + gid * 8) = *(const uint4*)v;
}

// ------- Fused 3x3 conv: 8-row x 128-wide strips, ci-split, 2 blk/CU -------
constexpr int RSB  = 136 * 16;      // 2176 B per LDS row
constexpr int BUFB = 10 * RSB;      // 21760 B per buffer

__global__ __launch_bounds__(512, 4) void conv_fused_k(
    const float* __restrict__ x, const unsigned short* __restrict__ wp,
    const float* __restrict__ cb, float* __restrict__ part) {
  __shared__ __align__(16) char xs[2 * BUFB];     // 43520 B
  const int tid  = threadIdx.x;
  const int wid  = tid >> 6, lane = tid & 63;
  const int q    = lane >> 4, p = lane & 15;
  const int ro   = wid;                            // out-row within strip

  // XCD-swizzle: each XCD owns a contiguous 64-row band (both ci-halves)
  const int bid = blockIdx.x;
  const int xcd = bid & 7, idx = bid >> 3;
  const int vstrip = xcd * 8 + (idx & 7);
  const int col    = (idx >> 3) & 3;
  const int half   = idx >> 5;                     // ci-half 0/1
  const int h0 = vstrip * 8, w0 = col * 128;

  // ---- staging unit descriptors (t-invariant): 680 units ----
  const int row1 = tid / 68, rem1 = tid - row1 * 68;
  const int cc1 = rem1 >> 1, h41 = rem1 & 1;
  const int gh1 = h0 - 1 + row1, gpx1 = w0 + cc1 * 4 - 4;
  const bool ok1 = ((unsigned)gh1 < 512u) && ((unsigned)gpx1 < 509u);
  const float* gp1 = x + (size_t)(half * 128 + h41 * 4) * HW
                   + min(max(gh1, 0), 511) * 512 + min(max(gpx1, 0), 508);
  const int wb1 = row1 * RSB + cc1 * 64 + h41 * 8;

  const int u2 = 512 + tid;
  const bool act2 = (tid < 168);
  const int row2 = u2 / 68, rem2 = u2 - row2 * 68;
  const int cc2 = rem2 >> 1, h42 = rem2 & 1;
  const int gh2 = h0 - 1 + row2, gpx2 = w0 + cc2 * 4 - 4;
  const bool ok2 = act2 && ((unsigned)gh2 < 512u) && ((unsigned)gpx2 < 509u);
  const float* gp2 = x + (size_t)(half * 128 + h42 * 4) * HW
                   + min(max(gh2, 0), 511) * 512 + min(max(gpx2, 0), 508);
  const int wb2 = row2 * RSB + cc2 * 64 + h42 * 8;

  // ---- per-m LDS read offsets ----
  int mo[3];
#pragma unroll
  for (int m = 0; m < 3; ++m) {
    int tap = 4 * m + q; if (tap > 8) tap = 8;
    int dy = (tap * 11) >> 5;
    int dx = tap - 3 * dy;
    mo[m] = dy * RSB + dx * 16;
  }
  const int base0 = ro * RSB + (p + 3) * 16;

  fx4 S1a, S1b, S1c, S1d, S2a, S2b, S2c, S2d;

#define ISSUE(t)                                                          \
  { const float* g1_ = gp1 + (size_t)((t) * 8) * HW;                      \
    S1a = *(const fx4*)(g1_);                                             \
    S1b = *(const fx4*)(g1_ + (size_t)HW);                                \
    S1c = *(const fx4*)(g1_ + 2 * (size_t)HW);                            \
    S1d = *(const fx4*)(g1_ + 3 * (size_t)HW);                            \
    if (act2) {                                                           \
      const float* g2_ = gp2 + (size_t)((t) * 8) * HW;                    \
      S2a = *(const fx4*)(g2_);                                           \
      S2b = *(const fx4*)(g2_ + (size_t)HW);                              \
      S2c = *(const fx4*)(g2_ + 2 * (size_t)HW);                          \
      S2d = *(const fx4*)(g2_ + 3 * (size_t)HW);                          \
    } }

#define WRITE(tb_)                                                        \
  { _Pragma("unroll") for (int j_ = 0; j_ < 4; ++j_) {                    \
      ux2 v_;                                                             \
      v_.x = pk2(S1a[j_], S1b[j_]); v_.y = pk2(S1c[j_], S1d[j_]);         \
      if (!ok1) { v_.x = 0u; v_.y = 0u; }                                 \
      *(ux2*)(xs + swz((tb_) + wb1 + j_ * 16)) = v_;                      \
    }                                                                     \
    if (act2) {                                                           \
      _Pragma("unroll") for (int j_ = 0; j_ < 4; ++j_) {                  \
        ux2 v_;                                                           \
        v_.x = pk2(S2a[j_], S2b[j_]); v_.y = pk2(S2c[j_], S2d[j_]);       \
        if (!ok2) { v_.x = 0u; v_.y = 0u; }                               \
        *(ux2*)(xs + swz((tb_) + wb2 + j_ * 16)) = v_;                    \
      }                                                                   \
    } }

#define MFMA_PHASE(tb_)                                                   \
  { _Pragma("unroll") for (int kk = 0; kk < 8; ++kk) {                    \
      const int ab = (tb_) + base0 + kk * 256;                            \
      bfrag b0 = *(const bfrag*)(xs + swz(ab + mo[0]));                   \
      acc[kk] = __builtin_amdgcn_mfma_f32_16x16x32_bf16(a0, b0, acc[kk], 0, 0, 0); \
      bfrag b1 = *(const bfrag*)(xs + swz(ab + mo[1]));                   \
      acc[kk] = __builtin_amdgcn_mfma_f32_16x16x32_bf16(a1, b1, acc[kk], 0, 0, 0); \
      bfrag b2 = *(const bfrag*)(xs + swz(ab + mo[2]));                   \
      acc[kk] = __builtin_amdgcn_mfma_f32_16x16x32_bf16(a2, b2, acc[kk], 0, 0, 0); \
    } }

  ffrag acc[8];
#pragma unroll
  for (int i = 0; i < 8; ++i) acc[i] = ffrag{0.f, 0.f, 0.f, 0.f};

  ISSUE(0);
  WRITE(0);
  __syncthreads();

#pragma unroll 1
  for (int t = 0; t < 16; ++t) {
    const unsigned short* wpt =
        wp + (size_t)((half * 16 + t) * 3) * 512 + lane * 8;
    bfrag a0 = *(const bfrag*)(wpt);
    bfrag a1 = *(const bfrag*)(wpt + 512);
    bfrag a2 = *(const bfrag*)(wpt + 1024);

    if (t < 15) ISSUE(t + 1);          // next chunk flies across MFMAs

    MFMA_PHASE((t & 1) * BUFB);

    if (t < 15) {
      WRITE(((t + 1) & 1) * BUFB);     // vmcnt drain lands after compute
      __syncthreads();
    }
  }
#undef ISSUE
#undef WRITE
#undef MFMA_PHASE

  // epilogue: partial sums (f32); bias folded into half 0
  if (lane < 32) {
    float* pp = part + (size_t)half * 2097152;
    const int orow = h0 + ro;
#pragma unroll
    for (int kk = 0; kk < 8; ++kk)
#pragma unroll
      for (int reg = 0; reg < 4; ++reg) {
        int co = q * 4 + reg;
        float b = half ? 0.0f : cb[co];
        pp[co * HW + orow * 512 + w0 + kk * 16 + p] = acc[kk][reg] + b;
      }
  }
}

// --- Kernel B: sum partials -> xc, argmax one-hot -> 8x8 mean -> unfold ----
__global__ __launch_bounds__(256) void argmax_pool_unfold_k(
    const float* __restrict__ part, float* __restrict__ xc,
    float* __restrict__ U) {
  const int lane = threadIdx.x & 63;
  const int wv   = threadIdx.x >> 6;
  const int cell = blockIdx.x * 4 + wv;      // 0..4095
  const int hd = cell >> 6, wd = cell & 63;  // fm coords (64x64)
  const int h = hd * 8 + (lane >> 3), w = wd * 8 + (lane & 7);
  const int pix = h * 512 + w;
  const float* p1 = part + 2097152;

  float best = -1e30f;
  int bc = 0;
#pragma unroll
  for (int c = 0; c < 8; ++c) {
    float v = part[c * HW + pix] + p1[c * HW + pix];
    xc[c * HW + pix] = v;                    // materialize x_conv
    if (v > best) { best = v; bc = c; }      // first-max kept (strict >)
  }
  float myu = 0.f;
#pragma unroll
  for (int c = 0; c < 8; ++c) {
    unsigned long long mk = __ballot(bc == c);
    if (lane == c) myu = (float)__popcll(mk) * (1.0f / 64.0f);
  }
  if (lane < 8) {
    const int k = (hd & 7) * 8 + (wd & 7);   // kernel element
    const int m = (hd >> 3) * 8 + (wd >> 3); // patch position
    U[lane * 4096 + k * 64 + m] = myu;
  }
}

// ---- Kernel C (lean): att=(A/nz)·U, fold, 1x1, out=corr*x+x, attn copy ----
// 1024 blocks x 256 thr, 4 independent waves, NO barriers. U read directly
// from global (c-slice = 16 KB, L1/L2-resident; all 4 waves share it) --
// LDS staging of L2-fit data was pure overhead (R12 lesson).
__global__ __launch_bounds__(256) void att_fold_corr_k(
    const float* __restrict__ attn, const float* __restrict__ U,
    const float* __restrict__ cw, const float* __restrict__ cb,
    float* __restrict__ out, float* __restrict__ attn_out) {
  __shared__ float Ar[4][64];
  const int tid  = threadIdx.x;
  const int lane = tid & 63;
  const int wv   = tid >> 6;
  const int l    = blockIdx.x * 4 + wv;      // patch 0..4095
  const int hq = l >> 6, wq = l & 63;
  const int h = hq * 8 + (lane >> 3), w = wq * 8 + (lane & 7);

  float corrv[8];
#pragma unroll
  for (int c = 0; c < 8; ++c) {
    const int aidx = ((c << 12) + l) * 64 + lane;
    float av = attn[aidx];
    attn_out[aidx] = av;                     // output 1: verbatim copy
    unsigned long long nzm = __ballot(av != 0.0f);
    float inv = 1.0f / ((float)__popcll(nzm) + 1e-5f);
    Ar[wv][lane] = av * inv;                 // same-wave DS order: safe

    const float* u = U + c * 4096 + lane;    // wave reads 256B/instr, L1-hot
    float s0 = 0.f, s1 = 0.f;
#pragma unroll
    for (int k = 0; k < 64; k += 2) {
      s0 = fmaf(Ar[wv][k],     u[k * 64],      s0);
      s1 = fmaf(Ar[wv][k + 1], u[(k + 1) * 64], s1);
    }
    corrv[c] = s0 + s1;
  }

  const int pix = h * 512 + w;
#pragma unroll
  for (int d = 0; d < 8; ++d) {
    float s = cb[d];
#pragma unroll
    for (int c = 0; c < 8; ++c)
      s = fmaf(corrv[c], cw[d * 8 + c], s);
    float v = out[d * HW + pix];
    out[d * HW + pix] = fmaf(s, v, v);
  }
}

extern "C" void kernel_launch(void* const* d_in, const int* in_sizes, int n_in,
                              void* d_out, int out_size, void* d_ws, size_t ws_size,
                              hipStream_t stream) {
  const float* x    = (const float*)d_in[0];
  const float* attn = (const float*)d_in[1];
  const float* cw   = (const float*)d_in[2];
  const float* cb   = (const float*)d_in[3];
  const float* qw   = (const float*)d_in[4];
  const float* qb   = (const float*)d_in[5];
  float* out = (float*)d_out;

  char* ws = (char*)d_ws;
  unsigned short* wpack = (unsigned short*)ws;   // 96 frags * 1KB = 96 KB
  float* U    = (float*)(ws + 98304);            // 128 KB
  float* part = (float*)(ws + 98304 + 131072);   // 2 x 8 MB f32 partials
  float* xc = out;                               // x_conv lives in out[0:2M]

  pack_w_k<<<dim3(24), dim3(256), 0, stream>>>(cw, wpack);
  conv_fused_k<<<dim3(512), dim3(512), 0, stream>>>(x, wpack, cb, part);
  argmax_pool_unfold_k<<<dim3(1024), dim3(256), 0, stream>>>(part, xc, U);
  att_fold_corr_k<<<dim3(1024), dim3(256), 0, stream>>>(attn, U, qw, qb,
                                                        out, out + 2097152);
}

// Round 14
// 92.287 us; speedup vs baseline: 3.2930x; 1.0572x over previous
//
#include <hip/hip_runtime.h>

#define HW (512*512)

typedef __attribute__((ext_vector_type(8))) short bfrag;   // 8 x bf16
typedef __attribute__((ext_vector_type(4))) float ffrag;   // 4 x f32 acc
typedef __attribute__((ext_vector_type(4))) float fx4;
typedef __attribute__((ext_vector_type(4))) unsigned int ux4;
typedef __attribute__((ext_vector_type(2))) unsigned int ux2;

__device__ __forceinline__ unsigned short f2bf(float f) {
  unsigned int u = __float_as_uint(f);
  u += 0x7fffu + ((u >> 16) & 1u);        // round-to-nearest-even
  return (unsigned short)(u >> 16);
}
__device__ __forceinline__ unsigned int pk2(float a, float b) {
  return (unsigned int)f2bf(a) | ((unsigned int)f2bf(b) << 16);
}
__device__ __forceinline__ float bf2f(unsigned short us) {
  return __uint_as_float((unsigned int)us << 16);
}
// LDS address swizzle: XOR 16B-slot bits [7:4] with bits [11:8].
__device__ __forceinline__ int swz(int a) { return a ^ ((a >> 4) & 0xF0); }

// ---------- Kernel W: pack conv weights, taps folded into K ----------------
__global__ __launch_bounds__(256) void pack_w_k(
    const float* __restrict__ cw, unsigned short* __restrict__ wp) {
  int gid = blockIdx.x * 256 + threadIdx.x;
  if (gid >= 96 * 64) return;
  int fid = gid >> 6, lane = gid & 63;
  int t = fid / 3, m = fid - t * 3;
  int q = lane >> 4, co = lane & 15;
  int tap = 4 * m + q;
  unsigned short v[8];
#pragma unroll
  for (int j = 0; j < 8; ++j) {
    int ci = t * 8 + j;
    float f = (co < 8 && tap < 9) ? cw[(co * 256 + ci) * 9 + tap] : 0.0f;
    v[j] = f2bf(f);
  }
  *(uint4*)(wp + gid * 8) = *(const uint4*)v;
}

// ------- Fused 3x3 conv: 8-row x 128-wide strips, ci-split, 2 blk/CU -------
constexpr int RSB  = 136 * 16;      // 2176 B per LDS row
constexpr int BUFB = 10 * RSB;      // 21760 B per buffer

__global__ __launch_bounds__(512, 4) void conv_fused_k(
    const float* __restrict__ x, const unsigned short* __restrict__ wp,
    const float* __restrict__ cb, unsigned short* __restrict__ part) {
  __shared__ __align__(16) char xs[2 * BUFB];     // 43520 B
  const int tid  = threadIdx.x;
  const int wid  = tid >> 6, lane = tid & 63;
  const int q    = lane >> 4, p = lane & 15;
  const int ro   = wid;                            // out-row within strip

  // XCD-swizzle: each XCD owns a contiguous 64-row band (both ci-halves)
  const int bid = blockIdx.x;
  const int xcd = bid & 7, idx = bid >> 3;
  const int vstrip = xcd * 8 + (idx & 7);
  const int col    = (idx >> 3) & 3;
  const int half   = idx >> 5;                     // ci-half 0/1
  const int h0 = vstrip * 8, w0 = col * 128;

  // ---- staging unit descriptors (t-invariant): 680 units ----
  const int row1 = tid / 68, rem1 = tid - row1 * 68;
  const int cc1 = rem1 >> 1, h41 = rem1 & 1;
  const int gh1 = h0 - 1 + row1, gpx1 = w0 + cc1 * 4 - 4;
  const bool ok1 = ((unsigned)gh1 < 512u) && ((unsigned)gpx1 < 509u);
  const float* gp1 = x + (size_t)(half * 128 + h41 * 4) * HW
                   + min(max(gh1, 0), 511) * 512 + min(max(gpx1, 0), 508);
  const int wb1 = row1 * RSB + cc1 * 64 + h41 * 8;

  const int u2 = 512 + tid;
  const bool act2 = (tid < 168);
  const int row2 = u2 / 68, rem2 = u2 - row2 * 68;
  const int cc2 = rem2 >> 1, h42 = rem2 & 1;
  const int gh2 = h0 - 1 + row2, gpx2 = w0 + cc2 * 4 - 4;
  const bool ok2 = act2 && ((unsigned)gh2 < 512u) && ((unsigned)gpx2 < 509u);
  const float* gp2 = x + (size_t)(half * 128 + h42 * 4) * HW
                   + min(max(gh2, 0), 511) * 512 + min(max(gpx2, 0), 508);
  const int wb2 = row2 * RSB + cc2 * 64 + h42 * 8;

  // ---- per-m LDS read offsets ----
  int mo[3];
#pragma unroll
  for (int m = 0; m < 3; ++m) {
    int tap = 4 * m + q; if (tap > 8) tap = 8;
    int dy = (tap * 11) >> 5;
    int dx = tap - 3 * dy;
    mo[m] = dy * RSB + dx * 16;
  }
  const int base0 = ro * RSB + (p + 3) * 16;

  fx4 S1a, S1b, S1c, S1d, S2a, S2b, S2c, S2d;

#define ISSUE(t)                                                          \
  { const float* g1_ = gp1 + (size_t)((t) * 8) * HW;                      \
    S1a = *(const fx4*)(g1_);                                             \
    S1b = *(const fx4*)(g1_ + (size_t)HW);                                \
    S1c = *(const fx4*)(g1_ + 2 * (size_t)HW);                            \
    S1d = *(const fx4*)(g1_ + 3 * (size_t)HW);                            \
    if (act2) {                                                           \
      const float* g2_ = gp2 + (size_t)((t) * 8) * HW;                    \
      S2a = *(const fx4*)(g2_);                                           \
      S2b = *(const fx4*)(g2_ + (size_t)HW);                              \
      S2c = *(const fx4*)(g2_ + 2 * (size_t)HW);                          \
      S2d = *(const fx4*)(g2_ + 3 * (size_t)HW);                          \
    } }

#define WRITE(tb_)                                                        \
  { _Pragma("unroll") for (int j_ = 0; j_ < 4; ++j_) {                    \
      ux2 v_;                                                             \
      v_.x = pk2(S1a[j_], S1b[j_]); v_.y = pk2(S1c[j_], S1d[j_]);         \
      if (!ok1) { v_.x = 0u; v_.y = 0u; }                                 \
      *(ux2*)(xs + swz((tb_) + wb1 + j_ * 16)) = v_;                      \
    }                                                                     \
    if (act2) {                                                           \
      _Pragma("unroll") for (int j_ = 0; j_ < 4; ++j_) {                  \
        ux2 v_;                                                           \
        v_.x = pk2(S2a[j_], S2b[j_]); v_.y = pk2(S2c[j_], S2d[j_]);       \
        if (!ok2) { v_.x = 0u; v_.y = 0u; }                               \
        *(ux2*)(xs + swz((tb_) + wb2 + j_ * 16)) = v_;                    \
      }                                                                   \
    } }

#define MFMA_PHASE(tb_)                                                   \
  { _Pragma("unroll") for (int kk = 0; kk < 8; ++kk) {                    \
      const int ab = (tb_) + base0 + kk * 256;                            \
      bfrag b0 = *(const bfrag*)(xs + swz(ab + mo[0]));                   \
      acc[kk] = __builtin_amdgcn_mfma_f32_16x16x32_bf16(a0, b0, acc[kk], 0, 0, 0); \
      bfrag b1 = *(const bfrag*)(xs + swz(ab + mo[1]));                   \
      acc[kk] = __builtin_amdgcn_mfma_f32_16x16x32_bf16(a1, b1, acc[kk], 0, 0, 0); \
      bfrag b2 = *(const bfrag*)(xs + swz(ab + mo[2]));                   \
      acc[kk] = __builtin_amdgcn_mfma_f32_16x16x32_bf16(a2, b2, acc[kk], 0, 0, 0); \
    } }

  ffrag acc[8];
#pragma unroll
  for (int i = 0; i < 8; ++i) acc[i] = ffrag{0.f, 0.f, 0.f, 0.f};

  ISSUE(0);
  WRITE(0);
  __syncthreads();

#pragma unroll 1
  for (int t = 0; t < 16; ++t) {
    const unsigned short* wpt =
        wp + (size_t)((half * 16 + t) * 3) * 512 + lane * 8;
    bfrag a0 = *(const bfrag*)(wpt);
    bfrag a1 = *(const bfrag*)(wpt + 512);
    bfrag a2 = *(const bfrag*)(wpt + 1024);

    if (t < 15) ISSUE(t + 1);          // next chunk flies across MFMAs

    MFMA_PHASE((t & 1) * BUFB);

    if (t < 15) {
      WRITE(((t + 1) & 1) * BUFB);     // vmcnt drain lands after compute
      __syncthreads();
    }
  }
#undef ISSUE
#undef WRITE
#undef MFMA_PHASE

  // epilogue: bf16 partial sums; bias folded into half 0
  if (lane < 32) {
    unsigned short* pp = part + (size_t)half * (8 * HW);
    const int orow = h0 + ro;
#pragma unroll
    for (int kk = 0; kk < 8; ++kk)
#pragma unroll
      for (int reg = 0; reg < 4; ++reg) {
        int co = q * 4 + reg;
        float b = half ? 0.0f : cb[co];
        pp[co * HW + orow * 512 + w0 + kk * 16 + p] = f2bf(acc[kk][reg] + b);
      }
  }
}

// --- Kernel B: sum bf16 partials -> xc, argmax -> 8x8 mean -> unfold -------
__global__ __launch_bounds__(256) void argmax_pool_unfold_k(
    const unsigned short* __restrict__ part, float* __restrict__ xc,
    float* __restrict__ U) {
  const int lane = threadIdx.x & 63;
  const int wv   = threadIdx.x >> 6;
  const int cell = blockIdx.x * 4 + wv;      // 0..4095
  const int hd = cell >> 6, wd = cell & 63;  // fm coords (64x64)
  const int h = hd * 8 + (lane >> 3), w = wd * 8 + (lane & 7);
  const int pix = h * 512 + w;
  const unsigned short* p1 = part + 8 * HW;

  float best = -1e30f;
  int bc = 0;
#pragma unroll
  for (int c = 0; c < 8; ++c) {
    float v = bf2f(part[c * HW + pix]) + bf2f(p1[c * HW + pix]);
    xc[c * HW + pix] = v;                    // materialize x_conv
    if (v > best) { best = v; bc = c; }      // first-max kept (strict >)
  }
  float myu = 0.f;
#pragma unroll
  for (int c = 0; c < 8; ++c) {
    unsigned long long mk = __ballot(bc == c);
    if (lane == c) myu = (float)__popcll(mk) * (1.0f / 64.0f);
  }
  if (lane < 8) {
    const int k = (hd & 7) * 8 + (wd & 7);   // kernel element
    const int m = (hd >> 3) * 8 + (wd >> 3); // patch position
    U[lane * 4096 + k * 64 + m] = myu;
  }
}

// ---- Kernel C: att=(A/nz)·U, fold, 1x1, out=corr*x+x, attn copy -----------
// 512 blocks x 256 thr (4 waves), 2 patches per wave: each U-slice load
// feeds 4 fmaf (2 patches x 2 chains) -> L1 traffic halved vs R13. No
// barriers (same-wave LDS RAW ordering).
__global__ __launch_bounds__(256) void att_fold_corr_k(
    const float* __restrict__ attn, const float* __restrict__ U,
    const float* __restrict__ cw, const float* __restrict__ cb,
    float* __restrict__ out, float* __restrict__ attn_out) {
  __shared__ float Ar[4][2][64];
  const int tid  = threadIdx.x;
  const int lane = tid & 63;
  const int wv   = tid >> 6;
  const int l0   = blockIdx.x * 8 + wv * 2;  // patches l0, l0+1

  float corr0[8], corr1[8];
#pragma unroll
  for (int c = 0; c < 8; ++c) {
    const int a0i = ((c << 12) + l0) * 64 + lane;
    const int a1i = a0i + 64;
    float av0 = attn[a0i];
    float av1 = attn[a1i];
    attn_out[a0i] = av0;                     // output 1: verbatim copy
    attn_out[a1i] = av1;
    unsigned long long nz0 = __ballot(av0 != 0.0f);
    unsigned long long nz1 = __ballot(av1 != 0.0f);
    float inv0 = 1.0f / ((float)__popcll(nz0) + 1e-5f);
    float inv1 = 1.0f / ((float)__popcll(nz1) + 1e-5f);
    Ar[wv][0][lane] = av0 * inv0;            // same-wave DS order: safe
    Ar[wv][1][lane] = av1 * inv1;

    const float* u = U + c * 4096 + lane;    // slice shared by both patches
    float s00 = 0.f, s01 = 0.f, s10 = 0.f, s11 = 0.f;
#pragma unroll
    for (int k = 0; k < 64; k += 2) {
      float u0 = u[k * 64];
      float u1 = u[(k + 1) * 64];
      s00 = fmaf(Ar[wv][0][k],     u0, s00);
      s10 = fmaf(Ar[wv][1][k],     u0, s10);
      s01 = fmaf(Ar[wv][0][k + 1], u1, s01);
      s11 = fmaf(Ar[wv][1][k + 1], u1, s11);
    }
    corr0[c] = s00 + s01;
    corr1[c] = s10 + s11;
  }

#pragma unroll
  for (int i = 0; i < 2; ++i) {
    const int l = l0 + i;
    const int hq = l >> 6, wq = l & 63;
    const int pix = (hq * 8 + (lane >> 3)) * 512 + wq * 8 + (lane & 7);
#pragma unroll
    for (int d = 0; d < 8; ++d) {
      float s = cb[d];
#pragma unroll
      for (int c = 0; c < 8; ++c)
        s = fmaf(i ? corr1[c] : corr0[c], cw[d * 8 + c], s);
      float v = out[d * HW + pix];
      out[d * HW + pix] = fmaf(s, v, v);
    }
  }
}

extern "C" void kernel_launch(void* const* d_in, const int* in_sizes, int n_in,
                              void* d_out, int out_size, void* d_ws, size_t ws_size,
                              hipStream_t stream) {
  const float* x    = (const float*)d_in[0];
  const float* attn = (const float*)d_in[1];
  const float* cw   = (const float*)d_in[2];
  const float* cb   = (const float*)d_in[3];
  const float* qw   = (const float*)d_in[4];
  const float* qb   = (const float*)d_in[5];
  float* out = (float*)d_out;

  char* ws = (char*)d_ws;
  unsigned short* wpack = (unsigned short*)ws;      // 96 frags * 1KB = 96 KB
  float* U = (float*)(ws + 98304);                  // 128 KB
  unsigned short* part = (unsigned short*)(ws + 98304 + 131072); // 2x4MB bf16
  float* xc = out;                                  // x_conv lives in out[0:2M]

  pack_w_k<<<dim3(24), dim3(256), 0, stream>>>(cw, wpack);
  conv_fused_k<<<dim3(512), dim3(512), 0, stream>>>(x, wpack, cb, part);
  argmax_pool_unfold_k<<<dim3(1024), dim3(256), 0, stream>>>(part, xc, U);
  att_fold_corr_k<<<dim3(512), dim3(256), 0, stream>>>(attn, U, qw, qb,
                                                       out, out + 2097152);
}